// Round 1
// baseline (836.322 us; speedup 1.0000x reference)
//
#include <hip/hip_runtime.h>
#include <math.h>

#define D 128
#define GR 32  // rows per GEMM block

// ---------------- graph setup kernels ----------------

__global__ __launch_bounds__(256) void hist_k(const int* __restrict__ dst,
    const float* __restrict__ w, float* __restrict__ deg,
    int* __restrict__ cnt, int E) {
  int e = blockIdx.x * 256 + threadIdx.x;
  if (e < E) {
    int d = dst[e];
    atomicAdd(&deg[d], w[e]);
    atomicAdd(&cnt[d], 1);
  }
}

__global__ __launch_bounds__(256) void norm_k(const int* __restrict__ src,
    const int* __restrict__ dst, const float* __restrict__ w,
    const float* __restrict__ deg, float* __restrict__ nrm, int E) {
  int e = blockIdx.x * 256 + threadIdx.x;
  if (e < E) {
    float ds = deg[src[e]], dd = deg[dst[e]];
    float a = ds > 0.f ? rsqrtf(ds) : 0.f;
    float b = dd > 0.f ? rsqrtf(dd) : 0.f;
    nrm[e] = a * w[e] * b;
  }
}

// block-level exclusive scan: 1024 items / block (256 thr x 4)
__global__ __launch_bounds__(256) void scan1_k(const int* __restrict__ cnt,
    int* __restrict__ offs, int* __restrict__ bsum, int n) {
  __shared__ int ls[256];
  int t = threadIdx.x;
  int base = blockIdx.x * 1024 + t * 4;
  int v0 = 0, v1 = 0, v2 = 0, v3 = 0;
  if (base + 0 < n) v0 = cnt[base + 0];
  if (base + 1 < n) v1 = cnt[base + 1];
  if (base + 2 < n) v2 = cnt[base + 2];
  if (base + 3 < n) v3 = cnt[base + 3];
  int s = v0 + v1 + v2 + v3;
  ls[t] = s;
  __syncthreads();
  for (int off = 1; off < 256; off <<= 1) {
    int x = 0;
    if (t >= off) x = ls[t - off];
    __syncthreads();
    if (t >= off) ls[t] += x;
    __syncthreads();
  }
  int run = (t > 0) ? ls[t - 1] : 0;
  if (base + 0 < n) offs[base + 0] = run; run += v0;
  if (base + 1 < n) offs[base + 1] = run; run += v1;
  if (base + 2 < n) offs[base + 2] = run; run += v2;
  if (base + 3 < n) offs[base + 3] = run;
  if (t == 255) bsum[blockIdx.x] = ls[255];
}

__global__ void scan2_k(int* bsum, int nb) {
  if (threadIdx.x == 0) {
    int run = 0;
    for (int i = 0; i < nb; ++i) { int v = bsum[i]; bsum[i] = run; run += v; }
  }
}

__global__ __launch_bounds__(256) void scan3_k(int* __restrict__ offs,
    const int* __restrict__ bsum, int n, int total) {
  int t = threadIdx.x;
  int add = bsum[blockIdx.x];
  int base = blockIdx.x * 1024 + t * 4;
#pragma unroll
  for (int i = 0; i < 4; ++i)
    if (base + i < n) offs[base + i] += add;
  if (blockIdx.x == 0 && t == 0) offs[n] = total;
}

__global__ __launch_bounds__(256) void fill_k(const int* __restrict__ dst,
    const int* __restrict__ offs, int* __restrict__ cur,
    int* __restrict__ csr, int E) {
  int e = blockIdx.x * 256 + threadIdx.x;
  if (e < E) {
    int d = dst[e];
    int p = atomicAdd(&cur[d], 1);
    csr[offs[d] + p] = e;
  }
}

// ---------------- dense layer: H = X @ W + b (f32, in-place safe) ----------------

__global__ __launch_bounds__(256) void gemm_k(const float* __restrict__ X,
    const float* __restrict__ W, const float* __restrict__ b,
    float* __restrict__ H, int n) {
  __shared__ float Ws[D * D];    // 64 KB
  __shared__ float Xs[GR * D];   // 16 KB
  int t = threadIdx.x;
  const float4* W4 = (const float4*)W;
  float4* Ws4 = (float4*)Ws;
#pragma unroll
  for (int i = 0; i < 16; ++i) Ws4[t + 256 * i] = W4[t + 256 * i];
  int row0 = blockIdx.x * GR;
  int ntile = n - row0; if (ntile > GR) ntile = GR;
  const float4* X4 = (const float4*)(X + (size_t)row0 * D);
  float4* Xs4 = (float4*)Xs;
  for (int i = t; i < ntile * (D / 4); i += 256) Xs4[i] = X4[i];
  __syncthreads();

  int wave = t >> 6, lane = t & 63;
  int rbase = wave * 8;
  float2 acc[8];
#pragma unroll
  for (int r = 0; r < 8; ++r) acc[r] = make_float2(0.f, 0.f);
  const float2* Wr = (const float2*)Ws;  // [128][64] float2 rows
  for (int k = 0; k < D; k += 4) {
    float2 wv0 = Wr[(k + 0) * 64 + lane];
    float2 wv1 = Wr[(k + 1) * 64 + lane];
    float2 wv2 = Wr[(k + 2) * 64 + lane];
    float2 wv3 = Wr[(k + 3) * 64 + lane];
#pragma unroll
    for (int r = 0; r < 8; ++r) {
      float4 xv = *(const float4*)&Xs[(rbase + r) * D + k];
      acc[r].x = fmaf(xv.x, wv0.x, acc[r].x); acc[r].y = fmaf(xv.x, wv0.y, acc[r].y);
      acc[r].x = fmaf(xv.y, wv1.x, acc[r].x); acc[r].y = fmaf(xv.y, wv1.y, acc[r].y);
      acc[r].x = fmaf(xv.z, wv2.x, acc[r].x); acc[r].y = fmaf(xv.z, wv2.y, acc[r].y);
      acc[r].x = fmaf(xv.w, wv3.x, acc[r].x); acc[r].y = fmaf(xv.w, wv3.y, acc[r].y);
    }
  }
  float2 bv = ((const float2*)b)[lane];
#pragma unroll
  for (int r = 0; r < 8; ++r) {
    int row = rbase + r;
    if (row < ntile) {
      float2 o = make_float2(acc[r].x + bv.x, acc[r].y + bv.y);
      ((float2*)(H + (size_t)(row0 + row) * D))[lane] = o;
    }
  }
}

// ---------------- pull aggregation + PReLU (one wave per node) ----------------

__global__ __launch_bounds__(256) void agg_k(const float* __restrict__ Hin,
    const float* __restrict__ nrm, const int* __restrict__ csr,
    const int* __restrict__ offs, const int* __restrict__ src,
    const int* __restrict__ perm, const float* __restrict__ alpha,
    float* __restrict__ Out, int n) {
  int wave = threadIdx.x >> 6, lane = threadIdx.x & 63;
  int node = blockIdx.x * 4 + wave;
  if (node >= n) return;
  int beg = offs[node], end = offs[node + 1];
  float2 acc = make_float2(0.f, 0.f);
  int j = beg;
  for (; j + 2 <= end; j += 2) {
    int e0 = csr[j], e1 = csr[j + 1];
    float n0 = nrm[e0], n1 = nrm[e1];
    int s0 = src[e0], s1 = src[e1];
    if (perm) { s0 = perm[s0]; s1 = perm[s1]; }
    float2 h0 = ((const float2*)(Hin + (size_t)s0 * D))[lane];
    float2 h1 = ((const float2*)(Hin + (size_t)s1 * D))[lane];
    acc.x = fmaf(h0.x, n0, acc.x); acc.y = fmaf(h0.y, n0, acc.y);
    acc.x = fmaf(h1.x, n1, acc.x); acc.y = fmaf(h1.y, n1, acc.y);
  }
  if (j < end) {
    int e0 = csr[j];
    float n0 = nrm[e0];
    int s0 = src[e0];
    if (perm) s0 = perm[s0];
    float2 h0 = ((const float2*)(Hin + (size_t)s0 * D))[lane];
    acc.x = fmaf(h0.x, n0, acc.x); acc.y = fmaf(h0.y, n0, acc.y);
  }
  float2 al = ((const float2*)alpha)[lane];
  float2 o;
  o.x = acc.x >= 0.f ? acc.x : al.x * acc.x;
  o.y = acc.y >= 0.f ? acc.y : al.y * acc.y;
  ((float2*)(Out + (size_t)node * D))[lane] = o;
}

// ---------------- projection head ----------------

__global__ __launch_bounds__(256) void colsum_k(const float* __restrict__ Z,
    float* __restrict__ sums, int n) {
  int t = threadIdx.x;
  int col = t & 127, half = t >> 7;
  float acc = 0.f;
  for (int r = blockIdx.x * 2 + half; r < n; r += gridDim.x * 2)
    acc += Z[(size_t)r * D + col];
  __shared__ float s[256];
  s[t] = acc;
  __syncthreads();
  if (t < 128) atomicAdd(&sums[col], s[t] + s[t + 128]);
}

__global__ __launch_bounds__(128) void proj_k(const float* __restrict__ sums,
    const float* __restrict__ pW, const float* __restrict__ pb,
    float* __restrict__ g, float invN) {
  __shared__ float sg[128];
  int t = threadIdx.x;
  sg[t] = 1.f / (1.f + expf(-sums[t] * invN));
  __syncthreads();
  float a = pb[t];
  for (int k = 0; k < 128; ++k)
    a = fmaf(sg[k], pW[k * 128 + t], a);
  g[t] = a;
}

// ---------------- launcher ----------------

extern "C" void kernel_launch(void* const* d_in, const int* in_sizes, int n_in,
                              void* d_out, int out_size, void* d_ws, size_t ws_size,
                              hipStream_t stream) {
  const float* x   = (const float*)d_in[0];
  const int*   ei  = (const int*)d_in[1];
  const float* w   = (const float*)d_in[2];
  const int* perm1 = (const int*)d_in[3];
  const int* perm2 = (const int*)d_in[4];
  const float* W1a = (const float*)d_in[5];
  const float* b1a = (const float*)d_in[6];
  const float* W2a = (const float*)d_in[7];
  const float* b2a = (const float*)d_in[8];
  const float* al1 = (const float*)d_in[9];
  const float* W1b = (const float*)d_in[10];
  const float* b1b = (const float*)d_in[11];
  const float* W2b = (const float*)d_in[12];
  const float* b2b = (const float*)d_in[13];
  const float* al2 = (const float*)d_in[14];
  const float* pW  = (const float*)d_in[15];
  const float* pb  = (const float*)d_in[16];

  const int E = in_sizes[2];
  const int N = in_sizes[3];
  const int* srcA = ei;
  const int* dstA = ei + E;

  float* out = (float*)d_out;
  size_t ND = (size_t)N * D;
  float* z1  = out;
  float* z2  = out + ND;
  float* g1  = out + 2 * ND;
  float* g2  = g1 + D;
  float* z1n = g2 + D;
  float* z2n = z1n + ND;

  char* p = (char*)d_ws;
  auto carve = [&](size_t bytes) {
    char* r = p;
    p += (bytes + 255) & ~(size_t)255;
    return r;
  };
  float* deg  = (float*)carve((size_t)N * 4);
  float* nrm  = (float*)carve((size_t)E * 4);
  int*   cnt  = (int*)carve((size_t)N * 4);
  int*   offs = (int*)carve((size_t)(N + 1) * 4);
  int*   bsum = (int*)carve(256 * 4);
  int*   csr  = (int*)carve((size_t)E * 4);
  float* h1   = (float*)carve(ND * 4);
  float* mid  = (float*)carve(ND * 4);
  float* csum = (float*)carve(D * 4);

  int nbE = (E + 255) / 256;
  int nbS = (N + 1023) / 1024;
  int nbA = (N + 3) / 4;
  int nbG = (N + GR - 1) / GR;

  // --- graph normalization + CSR (shared by all 8 layers) ---
  hipMemsetAsync(deg, 0, (size_t)N * 4, stream);
  hipMemsetAsync(cnt, 0, (size_t)N * 4, stream);
  hist_k<<<nbE, 256, 0, stream>>>(dstA, w, deg, cnt, E);
  scan1_k<<<nbS, 256, 0, stream>>>(cnt, offs, bsum, N);
  scan2_k<<<1, 64, 0, stream>>>(bsum, nbS);
  scan3_k<<<nbS, 256, 0, stream>>>(offs, bsum, N, E);
  norm_k<<<nbE, 256, 0, stream>>>(srcA, dstA, w, deg, nrm, E);
  hipMemsetAsync(cnt, 0, (size_t)N * 4, stream);
  fill_k<<<nbE, 256, 0, stream>>>(dstA, offs, cnt, csr, E);

  // --- encoder a: h1a = x@W1a+b1a (shared by z1 and z1n via perm trick) ---
  gemm_k<<<nbG, 256, 0, stream>>>(x, W1a, b1a, h1, N);
  // z1
  agg_k<<<nbA, 256, 0, stream>>>(h1, nrm, csr, offs, srcA, nullptr, al1, mid, N);
  gemm_k<<<nbG, 256, 0, stream>>>(mid, W2a, b2a, mid, N);
  agg_k<<<nbA, 256, 0, stream>>>(mid, nrm, csr, offs, srcA, nullptr, al1, z1, N);
  // z1n (corrupted view: gather h1[perm1[src]])
  agg_k<<<nbA, 256, 0, stream>>>(h1, nrm, csr, offs, srcA, perm1, al1, mid, N);
  gemm_k<<<nbG, 256, 0, stream>>>(mid, W2a, b2a, mid, N);
  agg_k<<<nbA, 256, 0, stream>>>(mid, nrm, csr, offs, srcA, nullptr, al1, z1n, N);

  // --- encoder b ---
  gemm_k<<<nbG, 256, 0, stream>>>(x, W1b, b1b, h1, N);
  // z2
  agg_k<<<nbA, 256, 0, stream>>>(h1, nrm, csr, offs, srcA, nullptr, al2, mid, N);
  gemm_k<<<nbG, 256, 0, stream>>>(mid, W2b, b2b, mid, N);
  agg_k<<<nbA, 256, 0, stream>>>(mid, nrm, csr, offs, srcA, nullptr, al2, z2, N);
  // z2n
  agg_k<<<nbA, 256, 0, stream>>>(h1, nrm, csr, offs, srcA, perm2, al2, mid, N);
  gemm_k<<<nbG, 256, 0, stream>>>(mid, W2b, b2b, mid, N);
  agg_k<<<nbA, 256, 0, stream>>>(mid, nrm, csr, offs, srcA, nullptr, al2, z2n, N);

  // --- projection heads ---
  float invN = 1.0f / (float)N;
  hipMemsetAsync(csum, 0, D * 4, stream);
  colsum_k<<<256, 256, 0, stream>>>(z1, csum, N);
  proj_k<<<1, 128, 0, stream>>>(csum, pW, pb, g1, invN);
  hipMemsetAsync(csum, 0, D * 4, stream);
  colsum_k<<<256, 256, 0, stream>>>(z2, csum, N);
  proj_k<<<1, 128, 0, stream>>>(csum, pW, pb, g2, invN);
}

// Round 2
// 620.556 us; speedup vs baseline: 1.3477x; 1.3477x over previous
//
#include <hip/hip_runtime.h>
#include <hip/hip_bf16.h>
#include <math.h>

#define D 128
#define GR 32  // rows per GEMM block

// ---------------- graph setup kernels ----------------

__global__ __launch_bounds__(256) void hist_k(const int* __restrict__ dst,
    const float* __restrict__ w, float* __restrict__ deg,
    int* __restrict__ cnt, int E) {
  int e = blockIdx.x * 256 + threadIdx.x;
  if (e < E) {
    int d = dst[e];
    atomicAdd(&deg[d], w[e]);
    atomicAdd(&cnt[d], 1);
  }
}

__global__ __launch_bounds__(256) void norm_k(const int* __restrict__ src,
    const int* __restrict__ dst, const float* __restrict__ w,
    const float* __restrict__ deg, float* __restrict__ nrm, int E) {
  int e = blockIdx.x * 256 + threadIdx.x;
  if (e < E) {
    float ds = deg[src[e]], dd = deg[dst[e]];
    float a = ds > 0.f ? rsqrtf(ds) : 0.f;
    float b = dd > 0.f ? rsqrtf(dd) : 0.f;
    nrm[e] = a * w[e] * b;
  }
}

// block-level exclusive scan: 1024 items / block (256 thr x 4)
__global__ __launch_bounds__(256) void scan1_k(const int* __restrict__ cnt,
    int* __restrict__ offs, int* __restrict__ bsum, int n) {
  __shared__ int ls[256];
  int t = threadIdx.x;
  int base = blockIdx.x * 1024 + t * 4;
  int v0 = 0, v1 = 0, v2 = 0, v3 = 0;
  if (base + 0 < n) v0 = cnt[base + 0];
  if (base + 1 < n) v1 = cnt[base + 1];
  if (base + 2 < n) v2 = cnt[base + 2];
  if (base + 3 < n) v3 = cnt[base + 3];
  int s = v0 + v1 + v2 + v3;
  ls[t] = s;
  __syncthreads();
  for (int off = 1; off < 256; off <<= 1) {
    int x = 0;
    if (t >= off) x = ls[t - off];
    __syncthreads();
    if (t >= off) ls[t] += x;
    __syncthreads();
  }
  int run = (t > 0) ? ls[t - 1] : 0;
  if (base + 0 < n) offs[base + 0] = run; run += v0;
  if (base + 1 < n) offs[base + 1] = run; run += v1;
  if (base + 2 < n) offs[base + 2] = run; run += v2;
  if (base + 3 < n) offs[base + 3] = run;
  if (t == 255) bsum[blockIdx.x] = ls[255];
}

__global__ void scan2_k(int* bsum, int nb) {
  if (threadIdx.x == 0) {
    int run = 0;
    for (int i = 0; i < nb; ++i) { int v = bsum[i]; bsum[i] = run; run += v; }
  }
}

__global__ __launch_bounds__(256) void scan3_k(int* __restrict__ offs,
    const int* __restrict__ bsum, int n, int total) {
  int t = threadIdx.x;
  int add = bsum[blockIdx.x];
  int base = blockIdx.x * 1024 + t * 4;
#pragma unroll
  for (int i = 0; i < 4; ++i)
    if (base + i < n) offs[base + i] += add;
  if (blockIdx.x == 0 && t == 0) offs[n] = total;
}

// scatter edges into CSR order, pre-gathering src and norm (kills one indirection)
__global__ __launch_bounds__(256) void fill_k(const int* __restrict__ dst,
    const int* __restrict__ src, const float* __restrict__ nrm,
    const int* __restrict__ offs, int* __restrict__ cur,
    int* __restrict__ srcc, float* __restrict__ nrmc, int E) {
  int e = blockIdx.x * 256 + threadIdx.x;
  if (e < E) {
    int d = dst[e];
    int p = atomicAdd(&cur[d], 1);
    int pos = offs[d] + p;
    srcc[pos] = src[e];
    nrmc[pos] = nrm[e];
  }
}

// pre-apply permutations to CSR src (kills perm indirection in corrupted aggs)
__global__ __launch_bounds__(256) void permsrc_k(const int* __restrict__ srcc,
    const int* __restrict__ p1, const int* __restrict__ p2,
    int* __restrict__ s1, int* __restrict__ s2, int E) {
  int j = blockIdx.x * 256 + threadIdx.x;
  if (j < E) {
    int s = srcc[j];
    s1[j] = p1[s];
    s2[j] = p2[s];
  }
}

// ---------------- dense layer: Hb(bf16) = X(f32) @ W + b ----------------

__global__ __launch_bounds__(256) void gemm_k(const float* __restrict__ X,
    const float* __restrict__ W, const float* __restrict__ b,
    __hip_bfloat162* __restrict__ Hb, int n) {
  __shared__ float Ws[D * D];    // 64 KB
  __shared__ float Xs[GR * D];   // 16 KB
  int t = threadIdx.x;
  const float4* W4 = (const float4*)W;
  float4* Ws4 = (float4*)Ws;
#pragma unroll
  for (int i = 0; i < 16; ++i) Ws4[t + 256 * i] = W4[t + 256 * i];
  int row0 = blockIdx.x * GR;
  int ntile = n - row0; if (ntile > GR) ntile = GR;
  const float4* X4 = (const float4*)(X + (size_t)row0 * D);
  float4* Xs4 = (float4*)Xs;
  for (int i = t; i < ntile * (D / 4); i += 256) Xs4[i] = X4[i];
  __syncthreads();

  int wave = t >> 6, lane = t & 63;
  int rbase = wave * 8;
  float2 acc[8];
#pragma unroll
  for (int r = 0; r < 8; ++r) acc[r] = make_float2(0.f, 0.f);
  const float2* Wr = (const float2*)Ws;  // [128][64] float2 rows
  for (int k = 0; k < D; k += 4) {
    float2 wv0 = Wr[(k + 0) * 64 + lane];
    float2 wv1 = Wr[(k + 1) * 64 + lane];
    float2 wv2 = Wr[(k + 2) * 64 + lane];
    float2 wv3 = Wr[(k + 3) * 64 + lane];
#pragma unroll
    for (int r = 0; r < 8; ++r) {
      float4 xv = *(const float4*)&Xs[(rbase + r) * D + k];
      acc[r].x = fmaf(xv.x, wv0.x, acc[r].x); acc[r].y = fmaf(xv.x, wv0.y, acc[r].y);
      acc[r].x = fmaf(xv.y, wv1.x, acc[r].x); acc[r].y = fmaf(xv.y, wv1.y, acc[r].y);
      acc[r].x = fmaf(xv.z, wv2.x, acc[r].x); acc[r].y = fmaf(xv.z, wv2.y, acc[r].y);
      acc[r].x = fmaf(xv.w, wv3.x, acc[r].x); acc[r].y = fmaf(xv.w, wv3.y, acc[r].y);
    }
  }
  float2 bv = ((const float2*)b)[lane];
#pragma unroll
  for (int r = 0; r < 8; ++r) {
    int row = rbase + r;
    if (row < ntile) {
      float2 o = make_float2(acc[r].x + bv.x, acc[r].y + bv.y);
      Hb[(size_t)(row0 + row) * 64 + lane] = __float22bfloat162_rn(o);
    }
  }
}

// ---------------- pull aggregation + PReLU (one wave per node, bf16 gather) ----

__device__ __forceinline__ float bf_lo(unsigned u) { return __uint_as_float(u << 16); }
__device__ __forceinline__ float bf_hi(unsigned u) { return __uint_as_float(u & 0xffff0000u); }

__global__ __launch_bounds__(256) void agg_k(const unsigned* __restrict__ Hb,
    const float* __restrict__ nrmc, const int* __restrict__ srcc,
    const int* __restrict__ offs, const float* __restrict__ alpha,
    float* __restrict__ Out, int n) {
  int wave = threadIdx.x >> 6, lane = threadIdx.x & 63;
  int node = blockIdx.x * 4 + wave;
  if (node >= n) return;
  int beg = offs[node], end = offs[node + 1];
  float2 acc = make_float2(0.f, 0.f);
  int j = beg;
  for (; j + 4 <= end; j += 4) {
    int s0 = srcc[j + 0], s1 = srcc[j + 1], s2 = srcc[j + 2], s3 = srcc[j + 3];
    float n0 = nrmc[j + 0], n1 = nrmc[j + 1], n2 = nrmc[j + 2], n3 = nrmc[j + 3];
    unsigned u0 = Hb[(size_t)s0 * 64 + lane];
    unsigned u1 = Hb[(size_t)s1 * 64 + lane];
    unsigned u2 = Hb[(size_t)s2 * 64 + lane];
    unsigned u3 = Hb[(size_t)s3 * 64 + lane];
    acc.x = fmaf(bf_lo(u0), n0, acc.x); acc.y = fmaf(bf_hi(u0), n0, acc.y);
    acc.x = fmaf(bf_lo(u1), n1, acc.x); acc.y = fmaf(bf_hi(u1), n1, acc.y);
    acc.x = fmaf(bf_lo(u2), n2, acc.x); acc.y = fmaf(bf_hi(u2), n2, acc.y);
    acc.x = fmaf(bf_lo(u3), n3, acc.x); acc.y = fmaf(bf_hi(u3), n3, acc.y);
  }
  for (; j < end; ++j) {
    int s0 = srcc[j];
    float n0 = nrmc[j];
    unsigned u0 = Hb[(size_t)s0 * 64 + lane];
    acc.x = fmaf(bf_lo(u0), n0, acc.x); acc.y = fmaf(bf_hi(u0), n0, acc.y);
  }
  float2 al = ((const float2*)alpha)[lane];
  float2 o;
  o.x = acc.x >= 0.f ? acc.x : al.x * acc.x;
  o.y = acc.y >= 0.f ? acc.y : al.y * acc.y;
  ((float2*)(Out + (size_t)node * D))[lane] = o;
}

// ---------------- projection head ----------------

__global__ __launch_bounds__(256) void colsum_k(const float* __restrict__ Z,
    float* __restrict__ sums, int n) {
  int t = threadIdx.x;
  int col = t & 127, half = t >> 7;
  float acc = 0.f;
  for (int r = blockIdx.x * 2 + half; r < n; r += gridDim.x * 2)
    acc += Z[(size_t)r * D + col];
  __shared__ float s[256];
  s[t] = acc;
  __syncthreads();
  if (t < 128) atomicAdd(&sums[col], s[t] + s[t + 128]);
}

__global__ __launch_bounds__(128) void proj_k(const float* __restrict__ sums,
    const float* __restrict__ pW, const float* __restrict__ pb,
    float* __restrict__ g, float invN) {
  __shared__ float sg[128];
  int t = threadIdx.x;
  sg[t] = 1.f / (1.f + expf(-sums[t] * invN));
  __syncthreads();
  float a = pb[t];
  for (int k = 0; k < 128; ++k)
    a = fmaf(sg[k], pW[k * 128 + t], a);
  g[t] = a;
}

// ---------------- launcher ----------------

extern "C" void kernel_launch(void* const* d_in, const int* in_sizes, int n_in,
                              void* d_out, int out_size, void* d_ws, size_t ws_size,
                              hipStream_t stream) {
  const float* x   = (const float*)d_in[0];
  const int*   ei  = (const int*)d_in[1];
  const float* w   = (const float*)d_in[2];
  const int* perm1 = (const int*)d_in[3];
  const int* perm2 = (const int*)d_in[4];
  const float* W1a = (const float*)d_in[5];
  const float* b1a = (const float*)d_in[6];
  const float* W2a = (const float*)d_in[7];
  const float* b2a = (const float*)d_in[8];
  const float* al1 = (const float*)d_in[9];
  const float* W1b = (const float*)d_in[10];
  const float* b1b = (const float*)d_in[11];
  const float* W2b = (const float*)d_in[12];
  const float* b2b = (const float*)d_in[13];
  const float* al2 = (const float*)d_in[14];
  const float* pW  = (const float*)d_in[15];
  const float* pb  = (const float*)d_in[16];

  const int E = in_sizes[2];
  const int N = in_sizes[3];
  const int* srcA = ei;
  const int* dstA = ei + E;

  float* out = (float*)d_out;
  size_t ND = (size_t)N * D;
  float* z1  = out;
  float* z2  = out + ND;
  float* g1  = out + 2 * ND;
  float* g2  = g1 + D;
  float* z1n = g2 + D;
  float* z2n = z1n + ND;

  char* p = (char*)d_ws;
  auto carve = [&](size_t bytes) {
    char* r = p;
    p += (bytes + 255) & ~(size_t)255;
    return r;
  };
  float* deg   = (float*)carve((size_t)N * 4);
  float* nrm   = (float*)carve((size_t)E * 4);
  int*   cnt   = (int*)carve((size_t)N * 4);
  int*   offs  = (int*)carve((size_t)(N + 1) * 4);
  int*   bsum  = (int*)carve(256 * 4);
  int*   srcc  = (int*)carve((size_t)E * 4);
  float* nrmc  = (float*)carve((size_t)E * 4);
  int*   p1src = (int*)carve((size_t)E * 4);
  int*   p2src = (int*)carve((size_t)E * 4);
  __hip_bfloat162* h1b  = (__hip_bfloat162*)carve(ND * 2);
  __hip_bfloat162* midb = (__hip_bfloat162*)carve(ND * 2);
  float* mid  = (float*)carve(ND * 4);
  float* csum = (float*)carve(D * 4);

  int nbE = (E + 255) / 256;
  int nbS = (N + 1023) / 1024;
  int nbA = (N + 3) / 4;
  int nbG = (N + GR - 1) / GR;

  // --- graph normalization + CSR (shared by all 8 layers) ---
  hipMemsetAsync(deg, 0, (size_t)N * 4, stream);
  hipMemsetAsync(cnt, 0, (size_t)N * 4, stream);
  hist_k<<<nbE, 256, 0, stream>>>(dstA, w, deg, cnt, E);
  scan1_k<<<nbS, 256, 0, stream>>>(cnt, offs, bsum, N);
  scan2_k<<<1, 64, 0, stream>>>(bsum, nbS);
  scan3_k<<<nbS, 256, 0, stream>>>(offs, bsum, N, E);
  norm_k<<<nbE, 256, 0, stream>>>(srcA, dstA, w, deg, nrm, E);
  hipMemsetAsync(cnt, 0, (size_t)N * 4, stream);
  fill_k<<<nbE, 256, 0, stream>>>(dstA, srcA, nrm, offs, cnt, srcc, nrmc, E);
  permsrc_k<<<nbE, 256, 0, stream>>>(srcc, perm1, perm2, p1src, p2src, E);

  const unsigned* h1u  = (const unsigned*)h1b;
  const unsigned* midu = (const unsigned*)midb;

  // --- encoder a ---
  gemm_k<<<nbG, 256, 0, stream>>>(x, W1a, b1a, h1b, N);
  // z1
  agg_k<<<nbA, 256, 0, stream>>>(h1u, nrmc, srcc, offs, al1, mid, N);
  gemm_k<<<nbG, 256, 0, stream>>>(mid, W2a, b2a, midb, N);
  agg_k<<<nbA, 256, 0, stream>>>(midu, nrmc, srcc, offs, al1, z1, N);
  // z1n (corrupted view: src indices pre-permuted)
  agg_k<<<nbA, 256, 0, stream>>>(h1u, nrmc, p1src, offs, al1, mid, N);
  gemm_k<<<nbG, 256, 0, stream>>>(mid, W2a, b2a, midb, N);
  agg_k<<<nbA, 256, 0, stream>>>(midu, nrmc, srcc, offs, al1, z1n, N);

  // --- encoder b ---
  gemm_k<<<nbG, 256, 0, stream>>>(x, W1b, b1b, h1b, N);
  // z2
  agg_k<<<nbA, 256, 0, stream>>>(h1u, nrmc, srcc, offs, al2, mid, N);
  gemm_k<<<nbG, 256, 0, stream>>>(mid, W2b, b2b, midb, N);
  agg_k<<<nbA, 256, 0, stream>>>(midu, nrmc, srcc, offs, al2, z2, N);
  // z2n
  agg_k<<<nbA, 256, 0, stream>>>(h1u, nrmc, p2src, offs, al2, mid, N);
  gemm_k<<<nbG, 256, 0, stream>>>(mid, W2b, b2b, midb, N);
  agg_k<<<nbA, 256, 0, stream>>>(midu, nrmc, srcc, offs, al2, z2n, N);

  // --- projection heads ---
  float invN = 1.0f / (float)N;
  hipMemsetAsync(csum, 0, D * 4, stream);
  colsum_k<<<256, 256, 0, stream>>>(z1, csum, N);
  proj_k<<<1, 128, 0, stream>>>(csum, pW, pb, g1, invN);
  hipMemsetAsync(csum, 0, D * 4, stream);
  colsum_k<<<256, 256, 0, stream>>>(z2, csum, N);
  proj_k<<<1, 128, 0, stream>>>(csum, pW, pb, g2, invN);
}

// Round 3
// 420.607 us; speedup vs baseline: 1.9884x; 1.4754x over previous
//
#include <hip/hip_runtime.h>
#include <math.h>

#define D 128

typedef __attribute__((ext_vector_type(8))) short bf16x8;
typedef __attribute__((ext_vector_type(4))) float f32x4;

__device__ __forceinline__ unsigned short f2bf(float f) {
  unsigned u = __float_as_uint(f);
  unsigned r = (u + 0x7fffu + ((u >> 16) & 1u)) >> 16;
  return (unsigned short)r;
}
__device__ __forceinline__ unsigned pack2bf(float x, float y) {
  return (unsigned)f2bf(x) | ((unsigned)f2bf(y) << 16);
}
__device__ __forceinline__ float bf_lo(unsigned u) { return __uint_as_float(u << 16); }
__device__ __forceinline__ float bf_hi(unsigned u) { return __uint_as_float(u & 0xffff0000u); }

// ---------------- graph setup ----------------

__global__ __launch_bounds__(256) void hist_k(const int* __restrict__ dst,
    const float* __restrict__ w, float* __restrict__ deg,
    int* __restrict__ cnt, int E) {
  int e = blockIdx.x * 256 + threadIdx.x;
  if (e < E) {
    int d = dst[e];
    atomicAdd(&deg[d], w[e]);
    atomicAdd(&cnt[d], 1);
  }
}

__global__ __launch_bounds__(256) void scan1_k(const int* __restrict__ cnt,
    int* __restrict__ offs, int* __restrict__ bsum, int n) {
  __shared__ int ls[256];
  int t = threadIdx.x;
  int base = blockIdx.x * 1024 + t * 4;
  int v0 = 0, v1 = 0, v2 = 0, v3 = 0;
  if (base + 0 < n) v0 = cnt[base + 0];
  if (base + 1 < n) v1 = cnt[base + 1];
  if (base + 2 < n) v2 = cnt[base + 2];
  if (base + 3 < n) v3 = cnt[base + 3];
  int s = v0 + v1 + v2 + v3;
  ls[t] = s;
  __syncthreads();
  for (int off = 1; off < 256; off <<= 1) {
    int x = 0;
    if (t >= off) x = ls[t - off];
    __syncthreads();
    if (t >= off) ls[t] += x;
    __syncthreads();
  }
  int run = (t > 0) ? ls[t - 1] : 0;
  if (base + 0 < n) offs[base + 0] = run; run += v0;
  if (base + 1 < n) offs[base + 1] = run; run += v1;
  if (base + 2 < n) offs[base + 2] = run; run += v2;
  if (base + 3 < n) offs[base + 3] = run;
  if (t == 255) bsum[blockIdx.x] = ls[255];
}

__global__ void scan2_k(int* bsum, int nb) {
  if (threadIdx.x == 0) {
    int run = 0;
    for (int i = 0; i < nb; ++i) { int v = bsum[i]; bsum[i] = run; run += v; }
  }
}

__global__ __launch_bounds__(256) void scan3_k(int* __restrict__ offs,
    const int* __restrict__ bsum, int n, int total) {
  int t = threadIdx.x;
  int add = bsum[blockIdx.x];
  int base = blockIdx.x * 1024 + t * 4;
#pragma unroll
  for (int i = 0; i < 4; ++i)
    if (base + i < n) offs[base + i] += add;
  if (blockIdx.x == 0 && t == 0) offs[n] = total;
}

// fused: edge norm + CSR scatter + pre-permuted src indices
__global__ __launch_bounds__(256) void fillnorm_k(const int* __restrict__ src,
    const int* __restrict__ dst, const float* __restrict__ w,
    const float* __restrict__ deg, const int* __restrict__ perm1,
    const int* __restrict__ perm2, const int* __restrict__ offs,
    int* __restrict__ cur, int* __restrict__ srcc, float* __restrict__ nrmc,
    int* __restrict__ p1src, int* __restrict__ p2src, int E) {
  int e = blockIdx.x * 256 + threadIdx.x;
  if (e >= E) return;
  int s = src[e], d = dst[e];
  float ds = deg[s], dd = deg[d];
  float a = ds > 0.f ? rsqrtf(ds) : 0.f;
  float b = dd > 0.f ? rsqrtf(dd) : 0.f;
  float nr = a * w[e] * b;
  int p = atomicAdd(&cur[d], 1);
  int pos = offs[d] + p;
  srcc[pos] = s;
  nrmc[pos] = nr;
  p1src[pos] = perm1[s];
  p2src[pos] = perm2[s];
}

// ---------------- prep: x -> bf16, W -> per-lane MFMA fragment panels ----------------
// Fragment panel layout (16B units): unit u = ((kk/32)*8 + ct)*64 + lane holds
// B[k][n] for n = ct*16 + (lane&15), k = kk + (lane>>4)*8 + j, j=0..7 (bf16).

__global__ __launch_bounds__(256) void prep_k(const float* __restrict__ x,
    const float* __restrict__ W1a, const float* __restrict__ W2a,
    const float* __restrict__ W1b, const float* __restrict__ W2b,
    unsigned short* __restrict__ xb,
    unsigned short* __restrict__ F1a, unsigned short* __restrict__ F2a,
    unsigned short* __restrict__ F1b, unsigned short* __restrict__ F2b, int n) {
  int b = blockIdx.x, t = threadIdx.x;
  if (b < 32) {
    const float* Wsrc = (b < 8) ? W1a : (b < 16) ? W2a : (b < 24) ? W1b : W2b;
    unsigned short* Fdst = (b < 8) ? F1a : (b < 16) ? F2a : (b < 24) ? F1b : F2b;
    int u = ((b & 7) << 8) + t;          // 0..2047
    int l = u & 63;
    int ct = (u >> 6) & 7;
    int kk5 = u >> 9;                    // 0..3
    int nn = (ct << 4) + (l & 15);
    int kb = (kk5 << 5) + ((l >> 4) << 3);
    unsigned r0 = pack2bf(Wsrc[(kb + 0) * D + nn], Wsrc[(kb + 1) * D + nn]);
    unsigned r1 = pack2bf(Wsrc[(kb + 2) * D + nn], Wsrc[(kb + 3) * D + nn]);
    unsigned r2 = pack2bf(Wsrc[(kb + 4) * D + nn], Wsrc[(kb + 5) * D + nn]);
    unsigned r3 = pack2bf(Wsrc[(kb + 6) * D + nn], Wsrc[(kb + 7) * D + nn]);
    ((uint4*)Fdst)[u] = make_uint4(r0, r1, r2, r3);
  } else {
    size_t i = (size_t)(b - 32) * 256 + t;     // 8-elem unit
    size_t total = (size_t)n * (D / 8);
    if (i < total) {
      const float4* xs = (const float4*)x;
      float4 a = xs[i * 2], c = xs[i * 2 + 1];
      ((uint4*)xb)[i] = make_uint4(pack2bf(a.x, a.y), pack2bf(a.z, a.w),
                                   pack2bf(c.x, c.y), pack2bf(c.z, c.w));
    }
  }
}

// ---------------- MFMA GEMM: out(bf16) = A(bf16) @ W + b ----------------

__global__ __launch_bounds__(256) void gemm_k(const unsigned short* __restrict__ A,
    const unsigned short* __restrict__ Wf, const float* __restrict__ bias,
    unsigned short* __restrict__ outb, int n) {
  __shared__ __attribute__((aligned(16))) unsigned short Wl[16384];
  int t = threadIdx.x;
  {
    const uint4* srcp = (const uint4*)Wf;
    uint4* dstp = (uint4*)Wl;
#pragma unroll
    for (int i = 0; i < 8; ++i) dstp[t + (i << 8)] = srcp[t + (i << 8)];
  }
  __syncthreads();
  int wave = t >> 6, lane = t & 63;
  int row0 = (blockIdx.x << 6) + (wave << 4);
  int r = row0 + (lane & 15);
  int kg = (lane >> 4) << 3;
  f32x4 acc[8];
#pragma unroll
  for (int ct = 0; ct < 8; ++ct) {
    float bv = bias[(ct << 4) + (lane & 15)];
    acc[ct] = (f32x4){bv, bv, bv, bv};
  }
  bool inb = (r < n);
  const bf16x8* Wlv = (const bf16x8*)Wl;
#pragma unroll
  for (int ks = 0; ks < 4; ++ks) {
    bf16x8 a = {0, 0, 0, 0, 0, 0, 0, 0};
    if (inb) a = *(const bf16x8*)(A + (size_t)r * D + (ks << 5) + kg);
#pragma unroll
    for (int ct = 0; ct < 8; ++ct) {
      bf16x8 bb = Wlv[((ks << 3) + ct) * 64 + lane];
      acc[ct] = __builtin_amdgcn_mfma_f32_16x16x32_bf16(a, bb, acc[ct], 0, 0, 0);
    }
  }
  int orow = row0 + ((lane >> 4) << 2);
#pragma unroll
  for (int ct = 0; ct < 8; ++ct) {
    int col = (ct << 4) + (lane & 15);
#pragma unroll
    for (int v = 0; v < 4; ++v) {
      int rr = orow + v;
      if (rr < n) outb[(size_t)rr * D + col] = f2bf(acc[ct][v]);
    }
  }
}

// ---------------- pull aggregation + PReLU ----------------

template <bool BF16OUT>
__global__ __launch_bounds__(256) void agg_k(const unsigned* __restrict__ Hb,
    const float* __restrict__ nrmc, const int* __restrict__ srcc,
    const int* __restrict__ offs, const float* __restrict__ alpha,
    void* __restrict__ Out, int n) {
  int wave = threadIdx.x >> 6, lane = threadIdx.x & 63;
  int node = blockIdx.x * 4 + wave;
  if (node >= n) return;
  int beg = offs[node], end = offs[node + 1];
  float2 acc = make_float2(0.f, 0.f);
  int j = beg;
  for (; j + 4 <= end; j += 4) {
    int s0 = srcc[j + 0], s1 = srcc[j + 1], s2 = srcc[j + 2], s3 = srcc[j + 3];
    float n0 = nrmc[j + 0], n1 = nrmc[j + 1], n2 = nrmc[j + 2], n3 = nrmc[j + 3];
    unsigned u0 = Hb[(size_t)s0 * 64 + lane];
    unsigned u1 = Hb[(size_t)s1 * 64 + lane];
    unsigned u2 = Hb[(size_t)s2 * 64 + lane];
    unsigned u3 = Hb[(size_t)s3 * 64 + lane];
    acc.x = fmaf(bf_lo(u0), n0, acc.x); acc.y = fmaf(bf_hi(u0), n0, acc.y);
    acc.x = fmaf(bf_lo(u1), n1, acc.x); acc.y = fmaf(bf_hi(u1), n1, acc.y);
    acc.x = fmaf(bf_lo(u2), n2, acc.x); acc.y = fmaf(bf_hi(u2), n2, acc.y);
    acc.x = fmaf(bf_lo(u3), n3, acc.x); acc.y = fmaf(bf_hi(u3), n3, acc.y);
  }
  for (; j < end; ++j) {
    int s0 = srcc[j];
    float n0 = nrmc[j];
    unsigned u0 = Hb[(size_t)s0 * 64 + lane];
    acc.x = fmaf(bf_lo(u0), n0, acc.x); acc.y = fmaf(bf_hi(u0), n0, acc.y);
  }
  float2 al = ((const float2*)alpha)[lane];
  float2 o;
  o.x = acc.x >= 0.f ? acc.x : al.x * acc.x;
  o.y = acc.y >= 0.f ? acc.y : al.y * acc.y;
  if (BF16OUT)
    ((unsigned*)Out)[(size_t)node * 64 + lane] = pack2bf(o.x, o.y);
  else
    ((float2*)Out)[(size_t)node * 64 + lane] = o;
}

// merged layer-1 agg: normal + corrupted stream share srcc/nrmc pass
__global__ __launch_bounds__(256) void agg2_k(const unsigned* __restrict__ Hb,
    const float* __restrict__ nrmc, const int* __restrict__ srcc,
    const int* __restrict__ psrc, const int* __restrict__ offs,
    const float* __restrict__ alpha, unsigned* __restrict__ Out0,
    unsigned* __restrict__ Out1, int n) {
  int wave = threadIdx.x >> 6, lane = threadIdx.x & 63;
  int node = blockIdx.x * 4 + wave;
  if (node >= n) return;
  int beg = offs[node], end = offs[node + 1];
  float2 a0 = make_float2(0.f, 0.f), a1 = make_float2(0.f, 0.f);
  int j = beg;
  for (; j + 2 <= end; j += 2) {
    int s0 = srcc[j], s1 = srcc[j + 1];
    int p0 = psrc[j], p1 = psrc[j + 1];
    float n0 = nrmc[j], n1 = nrmc[j + 1];
    unsigned u0 = Hb[(size_t)s0 * 64 + lane];
    unsigned u1 = Hb[(size_t)s1 * 64 + lane];
    unsigned v0 = Hb[(size_t)p0 * 64 + lane];
    unsigned v1 = Hb[(size_t)p1 * 64 + lane];
    a0.x = fmaf(bf_lo(u0), n0, a0.x); a0.y = fmaf(bf_hi(u0), n0, a0.y);
    a0.x = fmaf(bf_lo(u1), n1, a0.x); a0.y = fmaf(bf_hi(u1), n1, a0.y);
    a1.x = fmaf(bf_lo(v0), n0, a1.x); a1.y = fmaf(bf_hi(v0), n0, a1.y);
    a1.x = fmaf(bf_lo(v1), n1, a1.x); a1.y = fmaf(bf_hi(v1), n1, a1.y);
  }
  if (j < end) {
    int s0 = srcc[j], p0 = psrc[j];
    float n0 = nrmc[j];
    unsigned u0 = Hb[(size_t)s0 * 64 + lane];
    unsigned v0 = Hb[(size_t)p0 * 64 + lane];
    a0.x = fmaf(bf_lo(u0), n0, a0.x); a0.y = fmaf(bf_hi(u0), n0, a0.y);
    a1.x = fmaf(bf_lo(v0), n0, a1.x); a1.y = fmaf(bf_hi(v0), n0, a1.y);
  }
  float2 al = ((const float2*)alpha)[lane];
  float2 o0, o1;
  o0.x = a0.x >= 0.f ? a0.x : al.x * a0.x;
  o0.y = a0.y >= 0.f ? a0.y : al.y * a0.y;
  o1.x = a1.x >= 0.f ? a1.x : al.x * a1.x;
  o1.y = a1.y >= 0.f ? a1.y : al.y * a1.y;
  Out0[(size_t)node * 64 + lane] = pack2bf(o0.x, o0.y);
  Out1[(size_t)node * 64 + lane] = pack2bf(o1.x, o1.y);
}

// ---------------- projection head ----------------

__global__ __launch_bounds__(256) void colsum_k(const float* __restrict__ Z,
    float* __restrict__ sums, int n) {
  int t = threadIdx.x;
  int col = t & 127, half = t >> 7;
  float acc = 0.f;
  for (int r = blockIdx.x * 2 + half; r < n; r += gridDim.x * 2)
    acc += Z[(size_t)r * D + col];
  __shared__ float s[256];
  s[t] = acc;
  __syncthreads();
  if (t < 128) atomicAdd(&sums[col], s[t] + s[t + 128]);
}

__global__ __launch_bounds__(128) void proj_k(const float* __restrict__ sums,
    const float* __restrict__ pW, const float* __restrict__ pb,
    float* __restrict__ g, float invN) {
  __shared__ float sg[128];
  int t = threadIdx.x;
  sg[t] = 1.f / (1.f + expf(-sums[t] * invN));
  __syncthreads();
  float a = pb[t];
  for (int k = 0; k < 128; ++k)
    a = fmaf(sg[k], pW[k * 128 + t], a);
  g[t] = a;
}

// ---------------- launcher ----------------

extern "C" void kernel_launch(void* const* d_in, const int* in_sizes, int n_in,
                              void* d_out, int out_size, void* d_ws, size_t ws_size,
                              hipStream_t stream) {
  const float* x   = (const float*)d_in[0];
  const int*   ei  = (const int*)d_in[1];
  const float* w   = (const float*)d_in[2];
  const int* perm1 = (const int*)d_in[3];
  const int* perm2 = (const int*)d_in[4];
  const float* W1a = (const float*)d_in[5];
  const float* b1a = (const float*)d_in[6];
  const float* W2a = (const float*)d_in[7];
  const float* b2a = (const float*)d_in[8];
  const float* al1 = (const float*)d_in[9];
  const float* W1b = (const float*)d_in[10];
  const float* b1b = (const float*)d_in[11];
  const float* W2b = (const float*)d_in[12];
  const float* b2b = (const float*)d_in[13];
  const float* al2 = (const float*)d_in[14];
  const float* pW  = (const float*)d_in[15];
  const float* pb  = (const float*)d_in[16];

  const int E = in_sizes[2];
  const int N = in_sizes[3];
  const int* srcA = ei;
  const int* dstA = ei + E;

  float* out = (float*)d_out;
  size_t ND = (size_t)N * D;
  float* z1  = out;
  float* z2  = out + ND;
  float* g1  = out + 2 * ND;
  float* g2  = g1 + D;
  float* z1n = g2 + D;
  float* z2n = z1n + ND;

  char* p = (char*)d_ws;
  auto carve = [&](size_t bytes) {
    char* r = p;
    p += (bytes + 255) & ~(size_t)255;
    return r;
  };
  float* deg   = (float*)carve((size_t)N * 4);
  int*   cnt   = (int*)carve((size_t)N * 4);
  int*   offs  = (int*)carve((size_t)(N + 1) * 4);
  int*   bsum  = (int*)carve(256 * 4);
  int*   srcc  = (int*)carve((size_t)E * 4);
  float* nrmc  = (float*)carve((size_t)E * 4);
  int*   p1src = (int*)carve((size_t)E * 4);
  int*   p2src = (int*)carve((size_t)E * 4);
  unsigned short* xb  = (unsigned short*)carve(ND * 2);
  unsigned short* h1b = (unsigned short*)carve(ND * 2);
  unsigned short* mA  = (unsigned short*)carve(ND * 2);
  unsigned short* mP  = (unsigned short*)carve(ND * 2);
  unsigned short* F1a = (unsigned short*)carve(32768);
  unsigned short* F2a = (unsigned short*)carve(32768);
  unsigned short* F1b = (unsigned short*)carve(32768);
  unsigned short* F2b = (unsigned short*)carve(32768);
  float* csum = (float*)carve(D * 4);

  int nbE = (E + 255) / 256;
  int nbS = (N + 1023) / 1024;
  int nbA = (N + 3) / 4;
  int nbG = (N + 63) / 64;
  int nbP = 32 + (int)(((size_t)N * (D / 8) + 255) / 256);

  // --- prep: bf16 x + fragment-packed weights ---
  prep_k<<<nbP, 256, 0, stream>>>(x, W1a, W2a, W1b, W2b, xb, F1a, F2a, F1b, F2b, N);

  // --- graph normalization + CSR (shared by all 8 layers) ---
  hipMemsetAsync(deg, 0, (size_t)N * 4, stream);
  hipMemsetAsync(cnt, 0, (size_t)N * 4, stream);
  hist_k<<<nbE, 256, 0, stream>>>(dstA, w, deg, cnt, E);
  scan1_k<<<nbS, 256, 0, stream>>>(cnt, offs, bsum, N);
  scan2_k<<<1, 64, 0, stream>>>(bsum, nbS);
  scan3_k<<<nbS, 256, 0, stream>>>(offs, bsum, N, E);
  hipMemsetAsync(cnt, 0, (size_t)N * 4, stream);
  fillnorm_k<<<nbE, 256, 0, stream>>>(srcA, dstA, w, deg, perm1, perm2, offs,
                                      cnt, srcc, nrmc, p1src, p2src, E);

  const unsigned* h1u = (const unsigned*)h1b;
  const unsigned* mAu = (const unsigned*)mA;
  const unsigned* mPu = (const unsigned*)mP;

  // --- encoder a ---
  gemm_k<<<nbG, 256, 0, stream>>>(xb, F1a, b1a, h1b, N);
  agg2_k<<<nbA, 256, 0, stream>>>(h1u, nrmc, srcc, p1src, offs, al1,
                                  (unsigned*)mA, (unsigned*)mP, N);
  gemm_k<<<nbG, 256, 0, stream>>>(mA, F2a, b2a, h1b, N);
  agg_k<false><<<nbA, 256, 0, stream>>>(h1u, nrmc, srcc, offs, al1, z1, N);
  gemm_k<<<nbG, 256, 0, stream>>>(mP, F2a, b2a, mA, N);
  agg_k<false><<<nbA, 256, 0, stream>>>(mAu, nrmc, srcc, offs, al1, z1n, N);

  // --- encoder b ---
  gemm_k<<<nbG, 256, 0, stream>>>(xb, F1b, b1b, h1b, N);
  agg2_k<<<nbA, 256, 0, stream>>>(h1u, nrmc, srcc, p2src, offs, al2,
                                  (unsigned*)mA, (unsigned*)mP, N);
  gemm_k<<<nbG, 256, 0, stream>>>(mA, F2b, b2b, h1b, N);
  agg_k<false><<<nbA, 256, 0, stream>>>(h1u, nrmc, srcc, offs, al2, z2, N);
  gemm_k<<<nbG, 256, 0, stream>>>(mP, F2b, b2b, mA, N);
  agg_k<false><<<nbA, 256, 0, stream>>>(mAu, nrmc, srcc, offs, al2, z2n, N);

  // --- projection heads ---
  float invN = 1.0f / (float)N;
  hipMemsetAsync(csum, 0, D * 4, stream);
  colsum_k<<<256, 256, 0, stream>>>(z1, csum, N);
  proj_k<<<1, 128, 0, stream>>>(csum, pW, pb, g1, invN);
  hipMemsetAsync(csum, 0, D * 4, stream);
  colsum_k<<<256, 256, 0, stream>>>(z2, csum, N);
  proj_k<<<1, 128, 0, stream>>>(csum, pW, pb, g2, invN);
}

// Round 4
// 323.943 us; speedup vs baseline: 2.5817x; 1.2984x over previous
//
#include <hip/hip_runtime.h>
#include <math.h>

#define D 128

typedef __attribute__((ext_vector_type(8))) short bf16x8;
typedef __attribute__((ext_vector_type(4))) float f32x4;

__device__ __forceinline__ unsigned short f2bf(float f) {
  unsigned u = __float_as_uint(f);
  unsigned r = (u + 0x7fffu + ((u >> 16) & 1u)) >> 16;
  return (unsigned short)r;
}
__device__ __forceinline__ unsigned pack2bf(float x, float y) {
  return (unsigned)f2bf(x) | ((unsigned)f2bf(y) << 16);
}
__device__ __forceinline__ float bf_lo(unsigned u) { return __uint_as_float(u << 16); }
__device__ __forceinline__ float bf_hi(unsigned u) { return __uint_as_float(u & 0xffff0000u); }

// ---------------- graph setup ----------------

__global__ __launch_bounds__(256) void hist_k(const int* __restrict__ dst,
    const float* __restrict__ w, float* __restrict__ deg,
    int* __restrict__ cnt, int E) {
  int e = blockIdx.x * 256 + threadIdx.x;
  if (e < E) {
    int d = dst[e];
    atomicAdd(&deg[d], w[e]);
    atomicAdd(&cnt[d], 1);
  }
}

__global__ __launch_bounds__(256) void scan1_k(const int* __restrict__ cnt,
    int* __restrict__ offs, int* __restrict__ bsum, int n) {
  __shared__ int ls[256];
  int t = threadIdx.x;
  int base = blockIdx.x * 1024 + t * 4;
  int v0 = 0, v1 = 0, v2 = 0, v3 = 0;
  if (base + 0 < n) v0 = cnt[base + 0];
  if (base + 1 < n) v1 = cnt[base + 1];
  if (base + 2 < n) v2 = cnt[base + 2];
  if (base + 3 < n) v3 = cnt[base + 3];
  int s = v0 + v1 + v2 + v3;
  ls[t] = s;
  __syncthreads();
  for (int off = 1; off < 256; off <<= 1) {
    int x = 0;
    if (t >= off) x = ls[t - off];
    __syncthreads();
    if (t >= off) ls[t] += x;
    __syncthreads();
  }
  int run = (t > 0) ? ls[t - 1] : 0;
  if (base + 0 < n) offs[base + 0] = run; run += v0;
  if (base + 1 < n) offs[base + 1] = run; run += v1;
  if (base + 2 < n) offs[base + 2] = run; run += v2;
  if (base + 3 < n) offs[base + 3] = run;
  if (t == 255) bsum[blockIdx.x] = ls[255];
}

__global__ void scan2_k(int* bsum, int nb) {
  if (threadIdx.x == 0) {
    int run = 0;
    for (int i = 0; i < nb; ++i) { int v = bsum[i]; bsum[i] = run; run += v; }
  }
}

__global__ __launch_bounds__(256) void scan3_k(int* __restrict__ offs,
    const int* __restrict__ bsum, int n, int total) {
  int t = threadIdx.x;
  int add = bsum[blockIdx.x];
  int base = blockIdx.x * 1024 + t * 4;
#pragma unroll
  for (int i = 0; i < 4; ++i)
    if (base + i < n) offs[base + i] += add;
  if (blockIdx.x == 0 && t == 0) offs[n] = total;
}

// fused: edge norm + CSR scatter + packed records {src,nrm} and {p1,p2}
__global__ __launch_bounds__(256) void fillnorm_k(const int* __restrict__ src,
    const int* __restrict__ dst, const float* __restrict__ w,
    const float* __restrict__ deg, const int* __restrict__ perm1,
    const int* __restrict__ perm2, const int* __restrict__ offs,
    int* __restrict__ cur, int2* __restrict__ ep, int2* __restrict__ pp, int E) {
  int e = blockIdx.x * 256 + threadIdx.x;
  if (e >= E) return;
  int s = src[e], d = dst[e];
  float ds = deg[s], dd = deg[d];
  float a = ds > 0.f ? rsqrtf(ds) : 0.f;
  float b = dd > 0.f ? rsqrtf(dd) : 0.f;
  float nr = a * w[e] * b;
  int p = atomicAdd(&cur[d], 1);
  int pos = offs[d] + p;
  ep[pos] = make_int2(s, __float_as_int(nr));
  pp[pos] = make_int2(perm1[s], perm2[s]);
}

// ---------------- prep: x -> bf16, W -> per-lane MFMA fragment panels ----------------

__global__ __launch_bounds__(256) void prep_k(const float* __restrict__ x,
    const float* __restrict__ W1a, const float* __restrict__ W2a,
    const float* __restrict__ W1b, const float* __restrict__ W2b,
    unsigned short* __restrict__ xb,
    unsigned short* __restrict__ F1a, unsigned short* __restrict__ F2a,
    unsigned short* __restrict__ F1b, unsigned short* __restrict__ F2b, int n) {
  int b = blockIdx.x, t = threadIdx.x;
  if (b < 32) {
    const float* Wsrc = (b < 8) ? W1a : (b < 16) ? W2a : (b < 24) ? W1b : W2b;
    unsigned short* Fdst = (b < 8) ? F1a : (b < 16) ? F2a : (b < 24) ? F1b : F2b;
    int u = ((b & 7) << 8) + t;          // 0..2047
    int l = u & 63;
    int ct = (u >> 6) & 7;
    int kk5 = u >> 9;                    // 0..3
    int nn = (ct << 4) + (l & 15);
    int kb = (kk5 << 5) + ((l >> 4) << 3);
    unsigned r0 = pack2bf(Wsrc[(kb + 0) * D + nn], Wsrc[(kb + 1) * D + nn]);
    unsigned r1 = pack2bf(Wsrc[(kb + 2) * D + nn], Wsrc[(kb + 3) * D + nn]);
    unsigned r2 = pack2bf(Wsrc[(kb + 4) * D + nn], Wsrc[(kb + 5) * D + nn]);
    unsigned r3 = pack2bf(Wsrc[(kb + 6) * D + nn], Wsrc[(kb + 7) * D + nn]);
    ((uint4*)Fdst)[u] = make_uint4(r0, r1, r2, r3);
  } else {
    size_t i = (size_t)(b - 32) * 256 + t;     // 8-elem unit
    size_t total = (size_t)n * (D / 8);
    if (i < total) {
      const float4* xs = (const float4*)x;
      float4 a = xs[i * 2], c = xs[i * 2 + 1];
      ((uint4*)xb)[i] = make_uint4(pack2bf(a.x, a.y), pack2bf(a.z, a.w),
                                   pack2bf(c.x, c.y), pack2bf(c.z, c.w));
    }
  }
}

// ---------------- MFMA GEMM (multi-matrix via blockIdx.y) ----------------

struct GemmArgs {
  const unsigned short* A[4];
  const unsigned short* W[4];
  const float* bias[4];
  unsigned short* out[4];
};

__global__ __launch_bounds__(256) void gemm_k(GemmArgs ga, int n) {
  int y = blockIdx.y;
  const unsigned short* A = ga.A[y];
  const unsigned short* Wf = ga.W[y];
  const float* bias = ga.bias[y];
  unsigned short* outb = ga.out[y];

  __shared__ __attribute__((aligned(16))) unsigned short Wl[16384];
  int t = threadIdx.x;
  {
    const uint4* srcp = (const uint4*)Wf;
    uint4* dstp = (uint4*)Wl;
#pragma unroll
    for (int i = 0; i < 8; ++i) dstp[t + (i << 8)] = srcp[t + (i << 8)];
  }
  __syncthreads();
  int wave = t >> 6, lane = t & 63;
  int row0 = (blockIdx.x << 6) + (wave << 4);
  int r = row0 + (lane & 15);
  int kg = (lane >> 4) << 3;
  f32x4 acc[8];
#pragma unroll
  for (int ct = 0; ct < 8; ++ct) {
    float bv = bias[(ct << 4) + (lane & 15)];
    acc[ct] = (f32x4){bv, bv, bv, bv};
  }
  bool inb = (r < n);
  const bf16x8* Wlv = (const bf16x8*)Wl;
#pragma unroll
  for (int ks = 0; ks < 4; ++ks) {
    bf16x8 a = {0, 0, 0, 0, 0, 0, 0, 0};
    if (inb) a = *(const bf16x8*)(A + (size_t)r * D + (ks << 5) + kg);
#pragma unroll
    for (int ct = 0; ct < 8; ++ct) {
      bf16x8 bb = Wlv[((ks << 3) + ct) * 64 + lane];
      acc[ct] = __builtin_amdgcn_mfma_f32_16x16x32_bf16(a, bb, acc[ct], 0, 0, 0);
    }
  }
  int orow = row0 + ((lane >> 4) << 2);
#pragma unroll
  for (int ct = 0; ct < 8; ++ct) {
    int col = (ct << 4) + (lane & 15);
#pragma unroll
    for (int v = 0; v < 4; ++v) {
      int rr = orow + v;
      if (rr < n) outb[(size_t)rr * D + col] = f2bf(acc[ct][v]);
    }
  }
}

// ---------------- layer-1 agg: both encoders (grid.y), 2 gather streams/wave ----

__global__ __launch_bounds__(256) void aggL1_k(
    const unsigned* __restrict__ H0, const unsigned* __restrict__ H1,
    const int2* __restrict__ ep, const int2* __restrict__ pp,
    const int* __restrict__ offs,
    const float* __restrict__ al1, const float* __restrict__ al2,
    unsigned* __restrict__ oA0, unsigned* __restrict__ oP0,
    unsigned* __restrict__ oA1, unsigned* __restrict__ oP1, int n) {
  int y = blockIdx.y;
  const unsigned* Hb = y ? H1 : H0;
  const float* alpha = y ? al2 : al1;
  unsigned* OutA = y ? oA1 : oA0;
  unsigned* OutP = y ? oP1 : oP0;

  int wave = threadIdx.x >> 6, lane = threadIdx.x & 63;
  int node = blockIdx.x * 4 + wave;
  if (node >= n) return;
  int beg = offs[node], end = offs[node + 1];
  float2 a0 = make_float2(0.f, 0.f), a1 = make_float2(0.f, 0.f);
  int j = beg;
  for (; j + 2 <= end; j += 2) {
    int2 e0 = ep[j], e1 = ep[j + 1];
    int2 q0 = pp[j], q1 = pp[j + 1];
    float n0 = __int_as_float(e0.y), n1 = __int_as_float(e1.y);
    int p0 = y ? q0.y : q0.x;
    int p1 = y ? q1.y : q1.x;
    unsigned u0 = Hb[(size_t)e0.x * 64 + lane];
    unsigned u1 = Hb[(size_t)e1.x * 64 + lane];
    unsigned v0 = Hb[(size_t)p0 * 64 + lane];
    unsigned v1 = Hb[(size_t)p1 * 64 + lane];
    a0.x = fmaf(bf_lo(u0), n0, a0.x); a0.y = fmaf(bf_hi(u0), n0, a0.y);
    a0.x = fmaf(bf_lo(u1), n1, a0.x); a0.y = fmaf(bf_hi(u1), n1, a0.y);
    a1.x = fmaf(bf_lo(v0), n0, a1.x); a1.y = fmaf(bf_hi(v0), n0, a1.y);
    a1.x = fmaf(bf_lo(v1), n1, a1.x); a1.y = fmaf(bf_hi(v1), n1, a1.y);
  }
  if (j < end) {
    int2 e0 = ep[j];
    int2 q0 = pp[j];
    float n0 = __int_as_float(e0.y);
    int p0 = y ? q0.y : q0.x;
    unsigned u0 = Hb[(size_t)e0.x * 64 + lane];
    unsigned v0 = Hb[(size_t)p0 * 64 + lane];
    a0.x = fmaf(bf_lo(u0), n0, a0.x); a0.y = fmaf(bf_hi(u0), n0, a0.y);
    a1.x = fmaf(bf_lo(v0), n0, a1.x); a1.y = fmaf(bf_hi(v0), n0, a1.y);
  }
  float2 al = ((const float2*)alpha)[lane];
  float2 o0, o1;
  o0.x = a0.x >= 0.f ? a0.x : al.x * a0.x;
  o0.y = a0.y >= 0.f ? a0.y : al.y * a0.y;
  o1.x = a1.x >= 0.f ? a1.x : al.x * a1.x;
  o1.y = a1.y >= 0.f ? a1.y : al.y * a1.y;
  OutA[(size_t)node * 64 + lane] = pack2bf(o0.x, o0.y);
  OutP[(size_t)node * 64 + lane] = pack2bf(o1.x, o1.y);
}

// ---------------- final agg: 4 streams (grid.y), f32 out + fused colsum -------

__global__ __launch_bounds__(256) void aggF_k(
    const unsigned* __restrict__ I0, const unsigned* __restrict__ I1,
    const unsigned* __restrict__ I2, const unsigned* __restrict__ I3,
    const int2* __restrict__ ep, const int* __restrict__ offs,
    const float* __restrict__ al1, const float* __restrict__ al2,
    float* __restrict__ O0, float* __restrict__ O1,
    float* __restrict__ O2, float* __restrict__ O3,
    float* __restrict__ csum, int n) {
  int y = blockIdx.y;
  const unsigned* Hb = (y == 0) ? I0 : (y == 1) ? I1 : (y == 2) ? I2 : I3;
  float* Out = (y == 0) ? O0 : (y == 1) ? O1 : (y == 2) ? O2 : O3;
  const float* alpha = (y < 2) ? al1 : al2;
  int slot = (y == 0) ? 0 : (y == 2) ? 1 : -1;

  int wave = threadIdx.x >> 6, lane = threadIdx.x & 63;
  int node = blockIdx.x * 4 + wave;
  float2 o = make_float2(0.f, 0.f);
  if (node < n) {
    int beg = offs[node], end = offs[node + 1];
    float2 acc = make_float2(0.f, 0.f);
    int j = beg;
    for (; j + 4 <= end; j += 4) {
      int2 e0 = ep[j], e1 = ep[j + 1], e2 = ep[j + 2], e3 = ep[j + 3];
      unsigned u0 = Hb[(size_t)e0.x * 64 + lane];
      unsigned u1 = Hb[(size_t)e1.x * 64 + lane];
      unsigned u2 = Hb[(size_t)e2.x * 64 + lane];
      unsigned u3 = Hb[(size_t)e3.x * 64 + lane];
      float n0 = __int_as_float(e0.y), n1 = __int_as_float(e1.y);
      float n2 = __int_as_float(e2.y), n3 = __int_as_float(e3.y);
      acc.x = fmaf(bf_lo(u0), n0, acc.x); acc.y = fmaf(bf_hi(u0), n0, acc.y);
      acc.x = fmaf(bf_lo(u1), n1, acc.x); acc.y = fmaf(bf_hi(u1), n1, acc.y);
      acc.x = fmaf(bf_lo(u2), n2, acc.x); acc.y = fmaf(bf_hi(u2), n2, acc.y);
      acc.x = fmaf(bf_lo(u3), n3, acc.x); acc.y = fmaf(bf_hi(u3), n3, acc.y);
    }
    for (; j < end; ++j) {
      int2 e0 = ep[j];
      unsigned u0 = Hb[(size_t)e0.x * 64 + lane];
      float n0 = __int_as_float(e0.y);
      acc.x = fmaf(bf_lo(u0), n0, acc.x); acc.y = fmaf(bf_hi(u0), n0, acc.y);
    }
    float2 al = ((const float2*)alpha)[lane];
    o.x = acc.x >= 0.f ? acc.x : al.x * acc.x;
    o.y = acc.y >= 0.f ? acc.y : al.y * acc.y;
    ((float2*)(Out + (size_t)node * D))[lane] = o;
  }
  if (slot >= 0) {
    __shared__ float2 red[4][64];
    red[wave][lane] = o;
    __syncthreads();
    if (wave == 0) {
      float2 s0 = red[0][lane], s1 = red[1][lane];
      float2 s2 = red[2][lane], s3 = red[3][lane];
      float sx = s0.x + s1.x + s2.x + s3.x;
      float sy = s0.y + s1.y + s2.y + s3.y;
      float* base = csum + slot * 4096 + (blockIdx.x & 31) * 128;
      atomicAdd(&base[2 * lane], sx);
      atomicAdd(&base[2 * lane + 1], sy);
    }
  }
}

// ---------------- projection head ----------------

__global__ __launch_bounds__(128) void proj_k(const float* __restrict__ csum,
    const float* __restrict__ pW, const float* __restrict__ pb,
    float* __restrict__ g, float invN) {
  __shared__ float sg[128];
  int t = threadIdx.x;
  float s = 0.f;
#pragma unroll
  for (int i = 0; i < 32; ++i) s += csum[i * 128 + t];
  sg[t] = 1.f / (1.f + expf(-s * invN));
  __syncthreads();
  float a = pb[t];
  for (int k = 0; k < 128; ++k)
    a = fmaf(sg[k], pW[k * 128 + t], a);
  g[t] = a;
}

// ---------------- launcher ----------------

extern "C" void kernel_launch(void* const* d_in, const int* in_sizes, int n_in,
                              void* d_out, int out_size, void* d_ws, size_t ws_size,
                              hipStream_t stream) {
  const float* x   = (const float*)d_in[0];
  const int*   ei  = (const int*)d_in[1];
  const float* w   = (const float*)d_in[2];
  const int* perm1 = (const int*)d_in[3];
  const int* perm2 = (const int*)d_in[4];
  const float* W1a = (const float*)d_in[5];
  const float* b1a = (const float*)d_in[6];
  const float* W2a = (const float*)d_in[7];
  const float* b2a = (const float*)d_in[8];
  const float* al1 = (const float*)d_in[9];
  const float* W1b = (const float*)d_in[10];
  const float* b1b = (const float*)d_in[11];
  const float* W2b = (const float*)d_in[12];
  const float* b2b = (const float*)d_in[13];
  const float* al2 = (const float*)d_in[14];
  const float* pW  = (const float*)d_in[15];
  const float* pb  = (const float*)d_in[16];

  const int E = in_sizes[2];
  const int N = in_sizes[3];
  const int* srcA = ei;
  const int* dstA = ei + E;

  float* out = (float*)d_out;
  size_t ND = (size_t)N * D;
  float* z1  = out;
  float* z2  = out + ND;
  float* g1  = out + 2 * ND;
  float* g2  = g1 + D;
  float* z1n = g2 + D;
  float* z2n = z1n + ND;

  char* p = (char*)d_ws;
  auto carve = [&](size_t bytes) {
    char* r = p;
    p += (bytes + 255) & ~(size_t)255;
    return r;
  };
  // deg|cnt|cur contiguous for single memset
  float* deg  = (float*)carve((size_t)N * 4);
  int*   cnt  = (int*)carve((size_t)N * 4);
  int*   cur  = (int*)carve((size_t)N * 4);
  size_t zeroBytes = (size_t)((char*)(cur + N) - (char*)deg);
  int*   offs = (int*)carve((size_t)(N + 1) * 4);
  int*   bsum = (int*)carve(256 * 4);
  int2*  ep   = (int2*)carve((size_t)E * 8);
  int2*  pp   = (int2*)carve((size_t)E * 8);
  unsigned short* xb  = (unsigned short*)carve(ND * 2);
  unsigned short* h1a = (unsigned short*)carve(ND * 2);
  unsigned short* h1b = (unsigned short*)carve(ND * 2);
  unsigned short* yx  = (unsigned short*)carve(ND * 2);
  unsigned short* F1a = (unsigned short*)carve(32768);
  unsigned short* F2a = (unsigned short*)carve(32768);
  unsigned short* F1b = (unsigned short*)carve(32768);
  unsigned short* F2b = (unsigned short*)carve(32768);
  float* csum = (float*)carve(2 * 32 * 128 * 4);

  // layer-1 agg outputs live in z1n / z2n output regions (dead before AGGF writes)
  unsigned short* mAa = (unsigned short*)z1n;
  unsigned short* mPa = (unsigned short*)z1n + ND;
  unsigned short* mAb = (unsigned short*)z2n;
  unsigned short* mPb = (unsigned short*)z2n + ND;

  int nbE = (E + 255) / 256;
  int nbS = (N + 1023) / 1024;
  int nbA = (N + 3) / 4;
  int nbG = (N + 63) / 64;
  int nbP = 32 + (int)(((size_t)N * (D / 8) + 255) / 256);

  // --- prep + graph setup ---
  prep_k<<<nbP, 256, 0, stream>>>(x, W1a, W2a, W1b, W2b, xb, F1a, F2a, F1b, F2b, N);
  hipMemsetAsync(deg, 0, zeroBytes, stream);
  hipMemsetAsync(csum, 0, 2 * 32 * 128 * 4, stream);
  hist_k<<<nbE, 256, 0, stream>>>(dstA, w, deg, cnt, E);
  scan1_k<<<nbS, 256, 0, stream>>>(cnt, offs, bsum, N);
  scan2_k<<<1, 64, 0, stream>>>(bsum, nbS);
  scan3_k<<<nbS, 256, 0, stream>>>(offs, bsum, N, E);
  fillnorm_k<<<nbE, 256, 0, stream>>>(srcA, dstA, w, deg, perm1, perm2, offs,
                                      cur, ep, pp, E);

  // --- GEMM1: h1a = xb@W1a+b1a ; h1b = xb@W1b+b1b ---
  GemmArgs g1a;
  g1a.A[0] = xb;  g1a.W[0] = F1a; g1a.bias[0] = b1a; g1a.out[0] = h1a;
  g1a.A[1] = xb;  g1a.W[1] = F1b; g1a.bias[1] = b1b; g1a.out[1] = h1b;
  g1a.A[2] = xb;  g1a.W[2] = F1a; g1a.bias[2] = b1a; g1a.out[2] = h1a;
  g1a.A[3] = xb;  g1a.W[3] = F1a; g1a.bias[3] = b1a; g1a.out[3] = h1a;
  gemm_k<<<dim3(nbG, 2), 256, 0, stream>>>(g1a, N);

  // --- AGG layer 1: 4 streams (a:{I,P1}, b:{I,P2}) ---
  aggL1_k<<<dim3(nbA, 2), 256, 0, stream>>>(
      (const unsigned*)h1a, (const unsigned*)h1b, ep, pp, offs, al1, al2,
      (unsigned*)mAa, (unsigned*)mPa, (unsigned*)mAb, (unsigned*)mPb, N);

  // --- GEMM2: 4 matrices ---
  GemmArgs g2a;
  g2a.A[0] = mAa; g2a.W[0] = F2a; g2a.bias[0] = b2a; g2a.out[0] = xb;
  g2a.A[1] = mPa; g2a.W[1] = F2a; g2a.bias[1] = b2a; g2a.out[1] = h1a;
  g2a.A[2] = mAb; g2a.W[2] = F2b; g2a.bias[2] = b2b; g2a.out[2] = h1b;
  g2a.A[3] = mPb; g2a.W[3] = F2b; g2a.bias[3] = b2b; g2a.out[3] = yx;
  gemm_k<<<dim3(nbG, 4), 256, 0, stream>>>(g2a, N);

  // --- AGG final: 4 streams -> z1, z1n, z2, z2n (+ fused colsums for z1,z2) ---
  aggF_k<<<dim3(nbA, 4), 256, 0, stream>>>(
      (const unsigned*)xb, (const unsigned*)h1a, (const unsigned*)h1b,
      (const unsigned*)yx, ep, offs, al1, al2, z1, z1n, z2, z2n, csum, N);

  // --- projection heads ---
  float invN = 1.0f / (float)N;
  proj_k<<<1, 128, 0, stream>>>(csum, pW, pb, g1, invN);
  proj_k<<<1, 128, 0, stream>>>(csum + 4096, pW, pb, g2, invN);
}

// Round 5
// 288.026 us; speedup vs baseline: 2.9036x; 1.1247x over previous
//
#include <hip/hip_runtime.h>
#include <math.h>

#define D 128

typedef __attribute__((ext_vector_type(8))) short bf16x8;
typedef __attribute__((ext_vector_type(4))) float f32x4;

__device__ __forceinline__ unsigned short f2bf(float f) {
  unsigned u = __float_as_uint(f);
  unsigned r = (u + 0x7fffu + ((u >> 16) & 1u)) >> 16;
  return (unsigned short)r;
}
__device__ __forceinline__ unsigned pack2bf(float x, float y) {
  return (unsigned)f2bf(x) | ((unsigned)f2bf(y) << 16);
}
__device__ __forceinline__ float bf_lo(unsigned u) { return __uint_as_float(u << 16); }
__device__ __forceinline__ float bf_hi(unsigned u) { return __uint_as_float(u & 0xffff0000u); }

// ---------------- graph setup ----------------

__global__ __launch_bounds__(256) void hist_k(const int* __restrict__ dst,
    const float* __restrict__ w, float* __restrict__ deg,
    int* __restrict__ cnt, int E) {
  int e = blockIdx.x * 256 + threadIdx.x;
  if (e < E) {
    int d = dst[e];
    atomicAdd(&deg[d], w[e]);
    atomicAdd(&cnt[d], 1);
  }
}

__global__ __launch_bounds__(256) void scan1_k(const int* __restrict__ cnt,
    int* __restrict__ offs, int* __restrict__ bsum, int n) {
  __shared__ int ls[256];
  int t = threadIdx.x;
  int base = blockIdx.x * 1024 + t * 4;
  int v0 = 0, v1 = 0, v2 = 0, v3 = 0;
  if (base + 0 < n) v0 = cnt[base + 0];
  if (base + 1 < n) v1 = cnt[base + 1];
  if (base + 2 < n) v2 = cnt[base + 2];
  if (base + 3 < n) v3 = cnt[base + 3];
  int s = v0 + v1 + v2 + v3;
  ls[t] = s;
  __syncthreads();
  for (int off = 1; off < 256; off <<= 1) {
    int x = 0;
    if (t >= off) x = ls[t - off];
    __syncthreads();
    if (t >= off) ls[t] += x;
    __syncthreads();
  }
  int run = (t > 0) ? ls[t - 1] : 0;
  if (base + 0 < n) offs[base + 0] = run; run += v0;
  if (base + 1 < n) offs[base + 1] = run; run += v1;
  if (base + 2 < n) offs[base + 2] = run; run += v2;
  if (base + 3 < n) offs[base + 3] = run;
  if (t == 255) bsum[blockIdx.x] = ls[255];
}

__global__ void scan2_k(int* bsum, int nb) {
  if (threadIdx.x == 0) {
    int run = 0;
    for (int i = 0; i < nb; ++i) { int v = bsum[i]; bsum[i] = run; run += v; }
  }
}

__global__ __launch_bounds__(256) void scan3_k(int* __restrict__ offs,
    const int* __restrict__ bsum, int n, int total) {
  int t = threadIdx.x;
  int add = bsum[blockIdx.x];
  int base = blockIdx.x * 1024 + t * 4;
#pragma unroll
  for (int i = 0; i < 4; ++i)
    if (base + i < n) offs[base + i] += add;
  if (blockIdx.x == 0 && t == 0) offs[n] = total;
}

// fused: edge norm + CSR scatter + packed records {src,nrm} and {p1,p2}
__global__ __launch_bounds__(256) void fillnorm_k(const int* __restrict__ src,
    const int* __restrict__ dst, const float* __restrict__ w,
    const float* __restrict__ deg, const int* __restrict__ perm1,
    const int* __restrict__ perm2, const int* __restrict__ offs,
    int* __restrict__ cur, int2* __restrict__ ep, int2* __restrict__ pp, int E) {
  int e = blockIdx.x * 256 + threadIdx.x;
  if (e >= E) return;
  int s = src[e], d = dst[e];
  float ds = deg[s], dd = deg[d];
  float a = ds > 0.f ? rsqrtf(ds) : 0.f;
  float b = dd > 0.f ? rsqrtf(dd) : 0.f;
  float nr = a * w[e] * b;
  int p = atomicAdd(&cur[d], 1);
  int pos = offs[d] + p;
  ep[pos] = make_int2(s, __float_as_int(nr));
  pp[pos] = make_int2(perm1[s], perm2[s]);
}

// ---------------- prep: x -> bf16, W -> per-lane MFMA fragment panels ----------------

__global__ __launch_bounds__(256) void prep_k(const float* __restrict__ x,
    const float* __restrict__ W1a, const float* __restrict__ W2a,
    const float* __restrict__ W1b, const float* __restrict__ W2b,
    unsigned short* __restrict__ xb,
    unsigned short* __restrict__ F1a, unsigned short* __restrict__ F2a,
    unsigned short* __restrict__ F1b, unsigned short* __restrict__ F2b, int n) {
  int b = blockIdx.x, t = threadIdx.x;
  if (b < 32) {
    const float* Wsrc = (b < 8) ? W1a : (b < 16) ? W2a : (b < 24) ? W1b : W2b;
    unsigned short* Fdst = (b < 8) ? F1a : (b < 16) ? F2a : (b < 24) ? F1b : F2b;
    int u = ((b & 7) << 8) + t;          // 0..2047
    int l = u & 63;
    int ct = (u >> 6) & 7;
    int kk5 = u >> 9;                    // 0..3
    int nn = (ct << 4) + (l & 15);
    int kb = (kk5 << 5) + ((l >> 4) << 3);
    unsigned r0 = pack2bf(Wsrc[(kb + 0) * D + nn], Wsrc[(kb + 1) * D + nn]);
    unsigned r1 = pack2bf(Wsrc[(kb + 2) * D + nn], Wsrc[(kb + 3) * D + nn]);
    unsigned r2 = pack2bf(Wsrc[(kb + 4) * D + nn], Wsrc[(kb + 5) * D + nn]);
    unsigned r3 = pack2bf(Wsrc[(kb + 6) * D + nn], Wsrc[(kb + 7) * D + nn]);
    ((uint4*)Fdst)[u] = make_uint4(r0, r1, r2, r3);
  } else {
    size_t i = (size_t)(b - 32) * 256 + t;     // 8-elem unit
    size_t total = (size_t)n * (D / 8);
    if (i < total) {
      const float4* xs = (const float4*)x;
      float4 a = xs[i * 2], c = xs[i * 2 + 1];
      ((uint4*)xb)[i] = make_uint4(pack2bf(a.x, a.y), pack2bf(a.z, a.w),
                                   pack2bf(c.x, c.y), pack2bf(c.z, c.w));
    }
  }
}

// ---------------- MFMA GEMM (multi-matrix via blockIdx.y) ----------------

struct GemmArgs {
  const unsigned short* A[4];
  const unsigned short* W[4];
  const float* bias[4];
  unsigned short* out[4];
};

__global__ __launch_bounds__(256) void gemm_k(GemmArgs ga, int n) {
  int y = blockIdx.y;
  const unsigned short* A = ga.A[y];
  const unsigned short* Wf = ga.W[y];
  const float* bias = ga.bias[y];
  unsigned short* outb = ga.out[y];

  __shared__ __attribute__((aligned(16))) unsigned short Wl[16384];
  int t = threadIdx.x;
  {
    const uint4* srcp = (const uint4*)Wf;
    uint4* dstp = (uint4*)Wl;
#pragma unroll
    for (int i = 0; i < 8; ++i) dstp[t + (i << 8)] = srcp[t + (i << 8)];
  }
  __syncthreads();
  int wave = t >> 6, lane = t & 63;
  int row0 = (blockIdx.x << 6) + (wave << 4);
  int r = row0 + (lane & 15);
  int kg = (lane >> 4) << 3;
  f32x4 acc[8];
#pragma unroll
  for (int ct = 0; ct < 8; ++ct) {
    float bv = bias[(ct << 4) + (lane & 15)];
    acc[ct] = (f32x4){bv, bv, bv, bv};
  }
  bool inb = (r < n);
  const bf16x8* Wlv = (const bf16x8*)Wl;
#pragma unroll
  for (int ks = 0; ks < 4; ++ks) {
    bf16x8 a = {0, 0, 0, 0, 0, 0, 0, 0};
    if (inb) a = *(const bf16x8*)(A + (size_t)r * D + (ks << 5) + kg);
#pragma unroll
    for (int ct = 0; ct < 8; ++ct) {
      bf16x8 bb = Wlv[((ks << 3) + ct) * 64 + lane];
      acc[ct] = __builtin_amdgcn_mfma_f32_16x16x32_bf16(a, bb, acc[ct], 0, 0, 0);
    }
  }
  int orow = row0 + ((lane >> 4) << 2);
#pragma unroll
  for (int ct = 0; ct < 8; ++ct) {
    int col = (ct << 4) + (lane & 15);
#pragma unroll
    for (int v = 0; v < 4; ++v) {
      int rr = orow + v;
      if (rr < n) outb[(size_t)rr * D + col] = f2bf(acc[ct][v]);
    }
  }
}

// ---------------- 4-stream agg: one wave per node, 16 gathers in flight -------
// FINAL=false (layer1): streams {(T0,s),(T1,p1),(T2,s),(T3,p2)}, bf16 out.
// FINAL=true  (final) : streams {(Ti,s)}, f32 out + fused colsum for 0 and 2.

template <bool FINAL>
__global__ __launch_bounds__(256) void agg4_k(
    const unsigned* __restrict__ T0, const unsigned* __restrict__ T1,
    const unsigned* __restrict__ T2, const unsigned* __restrict__ T3,
    const int2* __restrict__ ep, const int2* __restrict__ pp,
    const int* __restrict__ offs,
    const float* __restrict__ al1, const float* __restrict__ al2,
    unsigned* __restrict__ O0b, unsigned* __restrict__ O1b,
    unsigned* __restrict__ O2b, unsigned* __restrict__ O3b,
    float* __restrict__ O0f, float* __restrict__ O1f,
    float* __restrict__ O2f, float* __restrict__ O3f,
    float* __restrict__ csum, int n) {
  int wave = threadIdx.x >> 6, lane = threadIdx.x & 63;
  int node = blockIdx.x * 4 + wave;
  float2 a0 = make_float2(0.f, 0.f), a1 = make_float2(0.f, 0.f);
  float2 a2 = make_float2(0.f, 0.f), a3 = make_float2(0.f, 0.f);

  if (node < n) {
    int beg = offs[node], end = offs[node + 1];
    int j = beg;
    for (; j + 4 <= end; j += 4) {
      unsigned g0[4], g1[4], g2[4], g3[4];
      float nr[4];
#pragma unroll
      for (int u = 0; u < 4; ++u) {
        int2 e = ep[j + u];
        nr[u] = __int_as_float(e.y);
        int s = e.x, ia = s, ib = s;
        if constexpr (!FINAL) {
          int2 q = pp[j + u];
          ia = q.x; ib = q.y;
        }
        g0[u] = T0[(size_t)s * 64 + lane];
        g1[u] = T1[(size_t)ia * 64 + lane];
        g2[u] = T2[(size_t)s * 64 + lane];
        g3[u] = T3[(size_t)ib * 64 + lane];
      }
#pragma unroll
      for (int u = 0; u < 4; ++u) {
        a0.x = fmaf(bf_lo(g0[u]), nr[u], a0.x); a0.y = fmaf(bf_hi(g0[u]), nr[u], a0.y);
        a1.x = fmaf(bf_lo(g1[u]), nr[u], a1.x); a1.y = fmaf(bf_hi(g1[u]), nr[u], a1.y);
        a2.x = fmaf(bf_lo(g2[u]), nr[u], a2.x); a2.y = fmaf(bf_hi(g2[u]), nr[u], a2.y);
        a3.x = fmaf(bf_lo(g3[u]), nr[u], a3.x); a3.y = fmaf(bf_hi(g3[u]), nr[u], a3.y);
      }
    }
    for (; j < end; ++j) {
      int2 e = ep[j];
      float nu = __int_as_float(e.y);
      int s = e.x, ia = s, ib = s;
      if constexpr (!FINAL) {
        int2 q = pp[j];
        ia = q.x; ib = q.y;
      }
      unsigned u0 = T0[(size_t)s * 64 + lane];
      unsigned u1 = T1[(size_t)ia * 64 + lane];
      unsigned u2 = T2[(size_t)s * 64 + lane];
      unsigned u3 = T3[(size_t)ib * 64 + lane];
      a0.x = fmaf(bf_lo(u0), nu, a0.x); a0.y = fmaf(bf_hi(u0), nu, a0.y);
      a1.x = fmaf(bf_lo(u1), nu, a1.x); a1.y = fmaf(bf_hi(u1), nu, a1.y);
      a2.x = fmaf(bf_lo(u2), nu, a2.x); a2.y = fmaf(bf_hi(u2), nu, a2.y);
      a3.x = fmaf(bf_lo(u3), nu, a3.x); a3.y = fmaf(bf_hi(u3), nu, a3.y);
    }
  }

  float2 alA = ((const float2*)al1)[lane];
  float2 alB = ((const float2*)al2)[lane];
  float2 o0 = make_float2(0.f, 0.f), o1 = o0, o2 = o0, o3 = o0;
  if (node < n) {
    o0.x = a0.x >= 0.f ? a0.x : alA.x * a0.x;  o0.y = a0.y >= 0.f ? a0.y : alA.y * a0.y;
    o1.x = a1.x >= 0.f ? a1.x : alA.x * a1.x;  o1.y = a1.y >= 0.f ? a1.y : alA.y * a1.y;
    o2.x = a2.x >= 0.f ? a2.x : alB.x * a2.x;  o2.y = a2.y >= 0.f ? a2.y : alB.y * a2.y;
    o3.x = a3.x >= 0.f ? a3.x : alB.x * a3.x;  o3.y = a3.y >= 0.f ? a3.y : alB.y * a3.y;
    size_t idx = (size_t)node * 64 + lane;
    if constexpr (FINAL) {
      ((float2*)O0f)[idx] = o0;
      ((float2*)O1f)[idx] = o1;
      ((float2*)O2f)[idx] = o2;
      ((float2*)O3f)[idx] = o3;
    } else {
      O0b[idx] = pack2bf(o0.x, o0.y);
      O1b[idx] = pack2bf(o1.x, o1.y);
      O2b[idx] = pack2bf(o2.x, o2.y);
      O3b[idx] = pack2bf(o3.x, o3.y);
    }
  }

  if constexpr (FINAL) {
    __shared__ float2 red[2][4][64];
    red[0][wave][lane] = o0;
    red[1][wave][lane] = o2;
    __syncthreads();
    if (wave < 2) {
      float2 s0 = red[wave][0][lane], s1 = red[wave][1][lane];
      float2 s2 = red[wave][2][lane], s3 = red[wave][3][lane];
      float sx = s0.x + s1.x + s2.x + s3.x;
      float sy = s0.y + s1.y + s2.y + s3.y;
      float* base = csum + wave * 4096 + (blockIdx.x & 31) * 128;
      atomicAdd(&base[2 * lane], sx);
      atomicAdd(&base[2 * lane + 1], sy);
    }
  }
}

// ---------------- projection head ----------------

__global__ __launch_bounds__(128) void proj_k(const float* __restrict__ csum,
    const float* __restrict__ pW, const float* __restrict__ pb,
    float* __restrict__ g, float invN) {
  __shared__ float sg[128];
  int t = threadIdx.x;
  float s = 0.f;
#pragma unroll
  for (int i = 0; i < 32; ++i) s += csum[i * 128 + t];
  sg[t] = 1.f / (1.f + expf(-s * invN));
  __syncthreads();
  float a = pb[t];
  for (int k = 0; k < 128; ++k)
    a = fmaf(sg[k], pW[k * 128 + t], a);
  g[t] = a;
}

// ---------------- launcher ----------------

extern "C" void kernel_launch(void* const* d_in, const int* in_sizes, int n_in,
                              void* d_out, int out_size, void* d_ws, size_t ws_size,
                              hipStream_t stream) {
  const float* x   = (const float*)d_in[0];
  const int*   ei  = (const int*)d_in[1];
  const float* w   = (const float*)d_in[2];
  const int* perm1 = (const int*)d_in[3];
  const int* perm2 = (const int*)d_in[4];
  const float* W1a = (const float*)d_in[5];
  const float* b1a = (const float*)d_in[6];
  const float* W2a = (const float*)d_in[7];
  const float* b2a = (const float*)d_in[8];
  const float* al1 = (const float*)d_in[9];
  const float* W1b = (const float*)d_in[10];
  const float* b1b = (const float*)d_in[11];
  const float* W2b = (const float*)d_in[12];
  const float* b2b = (const float*)d_in[13];
  const float* al2 = (const float*)d_in[14];
  const float* pW  = (const float*)d_in[15];
  const float* pb  = (const float*)d_in[16];

  const int E = in_sizes[2];
  const int N = in_sizes[3];
  const int* srcA = ei;
  const int* dstA = ei + E;

  float* out = (float*)d_out;
  size_t ND = (size_t)N * D;
  float* z1  = out;
  float* z2  = out + ND;
  float* g1  = out + 2 * ND;
  float* g2  = g1 + D;
  float* z1n = g2 + D;
  float* z2n = z1n + ND;

  char* p = (char*)d_ws;
  auto carve = [&](size_t bytes) {
    char* r = p;
    p += (bytes + 255) & ~(size_t)255;
    return r;
  };
  // deg|cnt|cur contiguous for single memset
  float* deg  = (float*)carve((size_t)N * 4);
  int*   cnt  = (int*)carve((size_t)N * 4);
  int*   cur  = (int*)carve((size_t)N * 4);
  size_t zeroBytes = (size_t)((char*)(cur + N) - (char*)deg);
  int*   offs = (int*)carve((size_t)(N + 1) * 4);
  int*   bsum = (int*)carve(256 * 4);
  int2*  ep   = (int2*)carve((size_t)E * 8);
  int2*  pp   = (int2*)carve((size_t)E * 8);
  unsigned short* xb  = (unsigned short*)carve(ND * 2);
  unsigned short* h1a = (unsigned short*)carve(ND * 2);
  unsigned short* h1b = (unsigned short*)carve(ND * 2);
  unsigned short* yx  = (unsigned short*)carve(ND * 2);
  unsigned short* F1a = (unsigned short*)carve(32768);
  unsigned short* F2a = (unsigned short*)carve(32768);
  unsigned short* F1b = (unsigned short*)carve(32768);
  unsigned short* F2b = (unsigned short*)carve(32768);
  float* csum = (float*)carve(2 * 32 * 128 * 4);

  // layer-1 agg outputs live in z1n / z2n output regions (dead before final agg writes)
  unsigned* mAa = (unsigned*)z1n;
  unsigned* mPa = (unsigned*)z1n + ND / 2;
  unsigned* mAb = (unsigned*)z2n;
  unsigned* mPb = (unsigned*)z2n + ND / 2;

  int nbE = (E + 255) / 256;
  int nbS = (N + 1023) / 1024;
  int nbA = (N + 3) / 4;
  int nbG = (N + 63) / 64;
  int nbP = 32 + (int)(((size_t)N * (D / 8) + 255) / 256);

  // --- prep + graph setup ---
  prep_k<<<nbP, 256, 0, stream>>>(x, W1a, W2a, W1b, W2b, xb, F1a, F2a, F1b, F2b, N);
  hipMemsetAsync(deg, 0, zeroBytes, stream);
  hipMemsetAsync(csum, 0, 2 * 32 * 128 * 4, stream);
  hist_k<<<nbE, 256, 0, stream>>>(dstA, w, deg, cnt, E);
  scan1_k<<<nbS, 256, 0, stream>>>(cnt, offs, bsum, N);
  scan2_k<<<1, 64, 0, stream>>>(bsum, nbS);
  scan3_k<<<nbS, 256, 0, stream>>>(offs, bsum, N, E);
  fillnorm_k<<<nbE, 256, 0, stream>>>(srcA, dstA, w, deg, perm1, perm2, offs,
                                      cur, ep, pp, E);

  // --- GEMM1: h1a = xb@W1a+b1a ; h1b = xb@W1b+b1b ---
  GemmArgs g1a;
  g1a.A[0] = xb;  g1a.W[0] = F1a; g1a.bias[0] = b1a; g1a.out[0] = h1a;
  g1a.A[1] = xb;  g1a.W[1] = F1b; g1a.bias[1] = b1b; g1a.out[1] = h1b;
  g1a.A[2] = xb;  g1a.W[2] = F1a; g1a.bias[2] = b1a; g1a.out[2] = h1a;
  g1a.A[3] = xb;  g1a.W[3] = F1a; g1a.bias[3] = b1a; g1a.out[3] = h1a;
  gemm_k<<<dim3(nbG, 2), 256, 0, stream>>>(g1a, N);

  // --- AGG layer 1: 4 streams in one wave: (h1a,s),(h1a,p1),(h1b,s),(h1b,p2) ---
  agg4_k<false><<<nbA, 256, 0, stream>>>(
      (const unsigned*)h1a, (const unsigned*)h1a,
      (const unsigned*)h1b, (const unsigned*)h1b,
      ep, pp, offs, al1, al2,
      mAa, mPa, mAb, mPb,
      nullptr, nullptr, nullptr, nullptr, nullptr, N);

  // --- GEMM2: 4 matrices ---
  GemmArgs g2a;
  g2a.A[0] = (const unsigned short*)mAa; g2a.W[0] = F2a; g2a.bias[0] = b2a; g2a.out[0] = xb;
  g2a.A[1] = (const unsigned short*)mPa; g2a.W[1] = F2a; g2a.bias[1] = b2a; g2a.out[1] = h1a;
  g2a.A[2] = (const unsigned short*)mAb; g2a.W[2] = F2b; g2a.bias[2] = b2b; g2a.out[2] = h1b;
  g2a.A[3] = (const unsigned short*)mPb; g2a.W[3] = F2b; g2a.bias[3] = b2b; g2a.out[3] = yx;
  gemm_k<<<dim3(nbG, 4), 256, 0, stream>>>(g2a, N);

  // --- AGG final: 4 streams -> z1, z1n, z2, z2n (+ fused colsums for z1,z2) ---
  agg4_k<true><<<nbA, 256, 0, stream>>>(
      (const unsigned*)xb, (const unsigned*)h1a,
      (const unsigned*)h1b, (const unsigned*)yx,
      ep, nullptr, offs, al1, al2,
      nullptr, nullptr, nullptr, nullptr,
      z1, z1n, z2, z2n, csum, N);

  // --- projection heads ---
  float invN = 1.0f / (float)N;
  proj_k<<<1, 128, 0, stream>>>(csum, pW, pb, g1, invN);
  proj_k<<<1, 128, 0, stream>>>(csum + 4096, pW, pb, g2, invN);
}